// Round 1
// baseline (539.393 us; speedup 1.0000x reference)
//
#include <hip/hip_runtime.h>
#include <hip/hip_bf16.h>
#include <stdint.h>

// CrossAttention: B=8, C=256, H=W=64 (N=4096), CR=64.
// out[b,c,n] = gamma * (V @ softmax(Q^T K, over keys)^T)[c,n] + source[b,c,n]
// Stage 1: proj kernel -> Qb [B][N][CR] bf16, Kb [B][N][CR] bf16, Vb [B][C][N] bf16 (+bias)
// Stage 2: flash-attention (QBLK=64 rows/block, KVBLK=64) with fused epilogue.

#define B_ 8
#define C_ 256
#define N_ 4096
#define CR_ 64

typedef unsigned short u16;
typedef __attribute__((ext_vector_type(8))) __bf16 bf16x8;
typedef __attribute__((ext_vector_type(8))) unsigned short ushort8;
typedef __attribute__((ext_vector_type(4))) float f32x4;

__device__ __forceinline__ u16 f2bf(float f) {
  union { float f; unsigned int u; } v; v.f = f;
  unsigned int r = (v.u + 0x7fffu + ((v.u >> 16) & 1u)) >> 16;
  return (u16)r;
}

// ---------------- Projection kernel ----------------
// grid (N/256, B, 6): z=0 -> Q (Wq, src), z=1 -> K (Wk, gui), z=2..5 -> V rows 64*(z-2) (Wv, gui, +bv)
__global__ __launch_bounds__(256) void proj_kernel(
    const float* __restrict__ src, const float* __restrict__ gui,
    const float* __restrict__ Wq, const float* __restrict__ Wk,
    const float* __restrict__ Wv, const float* __restrict__ bv,
    u16* __restrict__ Qb, u16* __restrict__ Kb, u16* __restrict__ Vb)
{
  __shared__ float Wl[64 * 256];  // 64 KB
  const int t = threadIdx.x;
  const int n = blockIdx.x * 256 + t;
  const int b = blockIdx.y;
  const int role = blockIdx.z;

  const float* W = (role == 0) ? Wq : (role == 1) ? Wk : (Wv + (size_t)(role - 2) * 64 * 256);
  const float* in = (role == 0) ? src : gui;

  for (int i = 0; i < 64; ++i) {
    int idx = i * 256 + t;
    Wl[idx] = W[idx];
  }
  __syncthreads();

  float acc[64];
#pragma unroll
  for (int q = 0; q < 64; ++q) acc[q] = 0.f;

  const float* inb = in + (size_t)b * C_ * N_ + n;
  for (int c0 = 0; c0 < 256; c0 += 8) {
    float s[8];
#pragma unroll
    for (int j = 0; j < 8; ++j) s[j] = inb[(size_t)(c0 + j) * N_];
#pragma unroll
    for (int q = 0; q < 64; ++q) {
      const float* wrow = &Wl[q * 256 + c0];
#pragma unroll
      for (int j = 0; j < 8; ++j) acc[q] = fmaf(wrow[j], s[j], acc[q]);
    }
  }

  if (role < 2) {
    u16* outp = ((role == 0) ? Qb : Kb) + ((size_t)(b * N_ + n)) * CR_;
#pragma unroll
    for (int q0 = 0; q0 < 64; q0 += 8) {
      ushort8 pk;
#pragma unroll
      for (int j = 0; j < 8; ++j) pk[j] = f2bf(acc[q0 + j]);
      *reinterpret_cast<ushort8*>(outp + q0) = pk;
    }
  } else {
    const int v0 = (role - 2) * 64;
    u16* outp = Vb + ((size_t)(b * C_ + v0)) * N_ + n;
#pragma unroll
    for (int q = 0; q < 64; ++q) outp[(size_t)q * N_] = f2bf(acc[q] + bv[v0 + q]);
  }
}

// ---------------- Flash attention kernel ----------------
// grid (N/64, B), 256 threads = 4 waves. Wave w owns q-rows [q0+16w, q0+16w+16).
// LDS rows padded to 72 bf16 (144 B) -> 2-way-max bank aliasing (free).
__global__ __launch_bounds__(256) void attn_kernel(
    const u16* __restrict__ Qb, const u16* __restrict__ Kb, const u16* __restrict__ Vb,
    const float* __restrict__ source, const float* __restrict__ gamma,
    float* __restrict__ out)
{
  __shared__ u16 Ks[64 * 72];    // 9216 B   [key][dim]
  __shared__ u16 Vs[256 * 72];   // 36864 B  [c][key]
  __shared__ u16 Ps[4 * 16 * 72];// 9216 B   per-wave P buffer [row][key]
  __shared__ float Tl[64 * 65];  // 16640 B  epilogue transpose tile

  const int t = threadIdx.x;
  const int lane = t & 63;
  const int wave = t >> 6;
  const int lg = lane >> 4;   // 0..3
  const int lm = lane & 15;   // 0..15
  const int b = blockIdx.y;
  const int q0 = blockIdx.x * 64;

  // Q fragments (A-operand): row = lm, k = lg*8 + j (+32 per kk)
  bf16x8 aq[2];
  {
    const u16* qp = Qb + ((size_t)(b * N_ + q0 + wave * 16 + lm) * CR_ + lg * 8);
    aq[0] = *reinterpret_cast<const bf16x8*>(qp);
    aq[1] = *reinterpret_cast<const bf16x8*>(qp + 32);
  }

  f32x4 accv[16];
  const f32x4 zero4 = {0.f, 0.f, 0.f, 0.f};
#pragma unroll
  for (int i = 0; i < 16; ++i) accv[i] = zero4;
  float mrow[4], lrow[4];
#pragma unroll
  for (int r = 0; r < 4; ++r) { mrow[r] = -1e30f; lrow[r] = 0.f; }

  for (int kt = 0; kt < 64; ++kt) {
    const int m0 = kt * 64;
    // stage K tile: 64 rows x 128B
#pragma unroll
    for (int i = 0; i < 2; ++i) {
      int idx = t + i * 256;
      int row = idx >> 3, seg = idx & 7;
      *reinterpret_cast<uint4*>(&Ks[row * 72 + seg * 8]) =
          *reinterpret_cast<const uint4*>(Kb + ((size_t)(b * N_ + m0 + row) * CR_ + seg * 8));
    }
    // stage V tile: 256 rows(c) x 64 keys
#pragma unroll
    for (int i = 0; i < 8; ++i) {
      int idx = t + i * 256;
      int row = idx >> 3, seg = idx & 7;
      *reinterpret_cast<uint4*>(&Vs[row * 72 + seg * 8]) =
          *reinterpret_cast<const uint4*>(Vb + ((size_t)(b * C_ + row) * N_ + m0 + seg * 8));
    }
    __syncthreads();

    // S = Q K^T : per wave 16 rows x 64 keys
    f32x4 sf[4];
#pragma unroll
    for (int kf = 0; kf < 4; ++kf) {
      sf[kf] = zero4;
#pragma unroll
      for (int kk = 0; kk < 2; ++kk) {
        bf16x8 bk = *reinterpret_cast<const bf16x8*>(&Ks[(kf * 16 + lm) * 72 + kk * 32 + lg * 8]);
        sf[kf] = __builtin_amdgcn_mfma_f32_16x16x32_bf16(aq[kk], bk, sf[kf], 0, 0, 0);
      }
    }

    // online softmax: row r of this lane = (lg*4 + r); reduce across 16 lanes (lm)
    float mx[4];
#pragma unroll
    for (int r = 0; r < 4; ++r) {
      float v = fmaxf(fmaxf(sf[0][r], sf[1][r]), fmaxf(sf[2][r], sf[3][r]));
      v = fmaxf(v, __shfl_xor(v, 1));
      v = fmaxf(v, __shfl_xor(v, 2));
      v = fmaxf(v, __shfl_xor(v, 4));
      v = fmaxf(v, __shfl_xor(v, 8));
      mx[r] = v;
    }
    float p[4][4];
    float sum[4];
    float scale[4];
#pragma unroll
    for (int r = 0; r < 4; ++r) {
      float mn = fmaxf(mrow[r], mx[r]);
      scale[r] = __expf(mrow[r] - mn);
      mrow[r] = mn;
      float s = 0.f;
#pragma unroll
      for (int kf = 0; kf < 4; ++kf) {
        float e = __expf(sf[kf][r] - mn);
        p[kf][r] = e;
        s += e;
      }
      s += __shfl_xor(s, 1);
      s += __shfl_xor(s, 2);
      s += __shfl_xor(s, 4);
      s += __shfl_xor(s, 8);
      sum[r] = s;
      lrow[r] = lrow[r] * scale[r] + sum[r];
    }
#pragma unroll
    for (int i = 0; i < 16; ++i) {
#pragma unroll
      for (int r = 0; r < 4; ++r) accv[i][r] *= scale[r];
    }

    // write P (D-layout) to per-wave LDS, read back in A-layout
    u16* pw = &Ps[wave * 16 * 72];
#pragma unroll
    for (int kf = 0; kf < 4; ++kf)
#pragma unroll
      for (int r = 0; r < 4; ++r)
        pw[(lg * 4 + r) * 72 + kf * 16 + lm] = f2bf(p[kf][r]);

#pragma unroll
    for (int kk = 0; kk < 2; ++kk) {
      bf16x8 pa = *reinterpret_cast<const bf16x8*>(&Ps[(wave * 16 + lm) * 72 + kk * 32 + lg * 8]);
#pragma unroll
      for (int cf = 0; cf < 16; ++cf) {
        bf16x8 bvf = *reinterpret_cast<const bf16x8*>(&Vs[(cf * 16 + lm) * 72 + kk * 32 + lg * 8]);
        accv[cf] = __builtin_amdgcn_mfma_f32_16x16x32_bf16(pa, bvf, accv[cf], 0, 0, 0);
      }
    }
    __syncthreads();
  }

  // epilogue: out[b,c,q0+n] = gamma/lsum * acc + source  (LDS transpose for coalescing)
  const float g = gamma[0];
  float invl[4];
#pragma unroll
  for (int r = 0; r < 4; ++r) invl[r] = g / lrow[r];

  for (int grp = 0; grp < 4; ++grp) {
#pragma unroll
    for (int cfl = 0; cfl < 4; ++cfl) {
      int cf = grp * 4 + cfl;
#pragma unroll
      for (int r = 0; r < 4; ++r)
        Tl[(wave * 16 + lg * 4 + r) * 65 + cfl * 16 + lm] = accv[cf][r] * invl[r];
    }
    __syncthreads();
    const int nl = t & 63;
    const int cl = t >> 6;
#pragma unroll
    for (int i = 0; i < 16; ++i) {
      int c = grp * 64 + cl + i * 4;
      size_t gi = ((size_t)(b * C_ + c)) * N_ + q0 + nl;
      out[gi] = Tl[nl * 65 + cl + i * 4] + source[gi];
    }
    __syncthreads();
  }
}

extern "C" void kernel_launch(void* const* d_in, const int* in_sizes, int n_in,
                              void* d_out, int out_size, void* d_ws, size_t ws_size,
                              hipStream_t stream) {
  const float* src = (const float*)d_in[0];
  const float* gui = (const float*)d_in[1];
  const float* Wq  = (const float*)d_in[2];
  const float* Wk  = (const float*)d_in[3];
  const float* Wv  = (const float*)d_in[4];
  const float* bv  = (const float*)d_in[5];
  const float* gm  = (const float*)d_in[6];
  float* out = (float*)d_out;

  u16* Qb = (u16*)d_ws;                         // 4 MB
  u16* Kb = Qb + (size_t)B_ * N_ * CR_;         // 4 MB
  u16* Vb = Kb + (size_t)B_ * N_ * CR_;         // 16 MB

  proj_kernel<<<dim3(N_ / 256, B_, 6), dim3(256), 0, stream>>>(src, gui, Wq, Wk, Wv, bv, Qb, Kb, Vb);
  attn_kernel<<<dim3(N_ / 64, B_), dim3(256), 0, stream>>>(Qb, Kb, Vb, src, gm, out);
}

// Round 2
// 266.310 us; speedup vs baseline: 2.0254x; 2.0254x over previous
//
#include <hip/hip_runtime.h>
#include <hip/hip_bf16.h>
#include <stdint.h>

// CrossAttention: B=8, C=256, H=W=64 (N=4096), CR=64.
// Stage 1: proj -> Qb [B][N][64] bf16, Kb [B][N][64] bf16, Vb [B][C][N] bf16 (+bias)
// Stage 2: flash-attn, QBLK=64 (4 waves x 16 rows), KVBLK=64, swapped-S softmax,
//          XOR-swizzled LDS + global_load_lds staging, 40960B LDS -> 4 blocks/CU.

#define B_ 8
#define C_ 256
#define N_ 4096
#define CR_ 64

typedef unsigned short u16;
typedef __attribute__((ext_vector_type(8))) __bf16 bf16x8;
typedef __attribute__((ext_vector_type(8))) unsigned short ushort8;
typedef __attribute__((ext_vector_type(4))) float f32x4;

__device__ __forceinline__ u16 f2bf(float f) {
  union { float f; unsigned int u; } v; v.f = f;
  unsigned int r = (v.u + 0x7fffu + ((v.u >> 16) & 1u)) >> 16;
  return (u16)r;
}
__device__ __forceinline__ unsigned int pack2bf(float a, float b) {
  return (unsigned int)f2bf(a) | ((unsigned int)f2bf(b) << 16);
}

typedef __attribute__((address_space(1))) const unsigned int gu32_t;
typedef __attribute__((address_space(3))) unsigned int lu32_t;
__device__ __forceinline__ void gll16(const void* g, void* l) {
  __builtin_amdgcn_global_load_lds((gu32_t*)g, (lu32_t*)l, 16, 0, 0);
}

// ---------------- Projection kernel ----------------
// grid (8, B, 12): role 0-1 -> Q chunks, 2-3 -> K chunks, 4-11 -> V chunks.
// Block: 32 out-channels x 512 pixels (2 px/thread).
__global__ __launch_bounds__(256) void proj_kernel(
    const float* __restrict__ src, const float* __restrict__ gui,
    const float* __restrict__ Wq, const float* __restrict__ Wk,
    const float* __restrict__ Wv, const float* __restrict__ bv,
    u16* __restrict__ Qb, u16* __restrict__ Kb, u16* __restrict__ Vb)
{
  __shared__ float Wl[32 * 256];  // 32 KB
  const int t = threadIdx.x;
  const int b = blockIdx.y;
  const int role = blockIdx.z;
  const int px0 = blockIdx.x * 512;

  const float* W;
  const float* in;
  if (role < 2)      { W = Wq + (size_t)role * 32 * 256;       in = src; }
  else if (role < 4) { W = Wk + (size_t)(role - 2) * 32 * 256; in = gui; }
  else               { W = Wv + (size_t)(role - 4) * 32 * 256; in = gui; }

#pragma unroll
  for (int i = 0; i < 32; ++i) Wl[i * 256 + t] = W[i * 256 + t];
  __syncthreads();

  float acc0[32], acc1[32];
#pragma unroll
  for (int q = 0; q < 32; ++q) { acc0[q] = 0.f; acc1[q] = 0.f; }

  const float* inb = in + (size_t)b * C_ * N_ + px0 + t;
  for (int c0 = 0; c0 < 256; c0 += 8) {
    float s0[8], s1[8];
#pragma unroll
    for (int j = 0; j < 8; ++j) {
      s0[j] = inb[(size_t)(c0 + j) * N_];
      s1[j] = inb[(size_t)(c0 + j) * N_ + 256];
    }
#pragma unroll
    for (int q = 0; q < 32; ++q) {
      const float* wr = &Wl[q * 256 + c0];
#pragma unroll
      for (int j = 0; j < 8; ++j) {
        acc0[q] = fmaf(wr[j], s0[j], acc0[q]);
        acc1[q] = fmaf(wr[j], s1[j], acc1[q]);
      }
    }
  }

  if (role < 4) {
    u16* dst = (role < 2) ? Qb : Kb;
    const int cbase = (role & 1) * 32;
#pragma unroll
    for (int h = 0; h < 2; ++h) {
      const float* ap = h ? acc1 : acc0;
      u16* op = dst + ((size_t)(b * N_ + px0 + h * 256 + t)) * CR_ + cbase;
#pragma unroll
      for (int g4 = 0; g4 < 4; ++g4) {
        ushort8 pk;
#pragma unroll
        for (int j = 0; j < 8; ++j) pk[j] = f2bf(ap[g4 * 8 + j]);
        *reinterpret_cast<ushort8*>(op + g4 * 8) = pk;
      }
    }
  } else {
    const int v0 = (role - 4) * 32;
#pragma unroll
    for (int q = 0; q < 32; ++q) {
      float bq = bv[v0 + q];
      u16* op = Vb + ((size_t)(b * C_ + v0 + q)) * N_ + px0 + t;
      op[0] = f2bf(acc0[q] + bq);
      op[256] = f2bf(acc1[q] + bq);
    }
  }
}

// ---------------- Flash attention kernel ----------------
// LDS layout (40960 B): [0,8192) K tile (64 rows x 128B), doubles as P buffer
// (wave w owns rows 16w..16w+15); [8192,40960) V tile (256 rows x 128B).
// Swizzle: phys 16B-chunk = logical chunk ^ (row & 7). Epilogue reuses LDS as Tl.
__global__ __launch_bounds__(256, 4) void attn_kernel(
    const u16* __restrict__ Qb, const u16* __restrict__ Kb, const u16* __restrict__ Vb,
    const float* __restrict__ source, const float* __restrict__ gamma,
    float* __restrict__ out)
{
  __shared__ uint4 smem4[2560];  // 40960 B
  char* smem = (char*)smem4;

  const int t = threadIdx.x;
  const int lane = t & 63;
  const int wave = t >> 6;
  const int lg = lane >> 4;   // 0..3
  const int lm = lane & 15;   // 0..15
  const int b = blockIdx.y;
  const int q0 = blockIdx.x * 64;

  // Q fragments: lane (lg,lm) holds Q[q0+wave*16+lm][kk*32+lg*8 .. +7]
  bf16x8 aq[2];
  {
    const u16* qp = Qb + ((size_t)(b * N_ + q0 + wave * 16 + lm)) * CR_ + lg * 8;
    aq[0] = *reinterpret_cast<const bf16x8*>(qp);
    aq[1] = *reinterpret_cast<const bf16x8*>(qp + 32);
  }

  // staging address precompute (byte offsets from per-batch bases)
  const int srow = t >> 3;   // 0..31
  const int cslot = t & 7;
  const char* KbB = (const char*)(Kb + (size_t)b * N_ * CR_);
  const char* VbB = (const char*)(Vb + (size_t)b * C_ * N_);
  unsigned int kgo[2], vgo[8];
#pragma unroll
  for (int i = 0; i < 2; ++i) {
    int row = i * 32 + srow;
    int cl = cslot ^ (row & 7);
    kgo[i] = (unsigned int)((row * CR_ + cl * 8) * 2);
  }
#pragma unroll
  for (int i = 0; i < 8; ++i) {
    int row = i * 32 + srow;
    int cl = cslot ^ (row & 7);
    vgo[i] = (unsigned int)((row * N_ + cl * 8) * 2);
  }

  f32x4 accv[16];
  const f32x4 zero4 = {0.f, 0.f, 0.f, 0.f};
#pragma unroll
  for (int i = 0; i < 16; ++i) accv[i] = zero4;
  float mrow = -1e30f, lrow = 0.f;

  const int sw = (lm & 7);  // swizzle key for this lane's row reads (row&7 == lm&7)

  for (int kt = 0; kt < 64; ++kt) {
    // ---- stage K (2x) and V (8x) via global_load_lds, pre-swizzled source ----
    const unsigned int kadd = (unsigned int)(kt * 64 * CR_ * 2);  // 64 rows per tile
    const unsigned int vadd = (unsigned int)(kt * 64 * 2);        // 64 keys per tile
#pragma unroll
    for (int i = 0; i < 2; ++i)
      gll16(KbB + kgo[i] + kadd, smem + i * 4096 + wave * 1024);
#pragma unroll
    for (int i = 0; i < 8; ++i)
      gll16(VbB + vgo[i] + vadd, smem + 8192 + i * 4096 + wave * 1024);
    __syncthreads();

    // ---- S^T = mfma(A=K, B=Q): lane holds S[q=lm][key=kf*16+lg*4+r] ----
    f32x4 sf[4];
#pragma unroll
    for (int kf = 0; kf < 4; ++kf) {
      sf[kf] = zero4;
#pragma unroll
      for (int kk = 0; kk < 2; ++kk) {
        bf16x8 bk = *reinterpret_cast<const bf16x8*>(
            smem + (kf * 16 + lm) * 128 + (((4 * kk + lg) ^ sw) << 4));
        sf[kf] = __builtin_amdgcn_mfma_f32_16x16x32_bf16(bk, aq[kk], sf[kf], 0, 0, 0);
      }
    }

    // ---- online softmax, row-local (16 vals) + 2 shfls over lg group ----
    float v = sf[0][0];
#pragma unroll
    for (int kf = 0; kf < 4; ++kf)
#pragma unroll
      for (int r = 0; r < 4; ++r) v = fmaxf(v, sf[kf][r]);
    v = fmaxf(v, __shfl_xor(v, 16));
    v = fmaxf(v, __shfl_xor(v, 32));
    float mn = fmaxf(mrow, v);
    float sc = __expf(mrow - mn);
    mrow = mn;
    float s = 0.f;
#pragma unroll
    for (int kf = 0; kf < 4; ++kf)
#pragma unroll
      for (int r = 0; r < 4; ++r) {
        float e = __expf(sf[kf][r] - mn);
        sf[kf][r] = e;
        s += e;
      }
    s += __shfl_xor(s, 16);
    s += __shfl_xor(s, 32);
    lrow = lrow * sc + s;
    float scr[4];
#pragma unroll
    for (int r = 0; r < 4; ++r) scr[r] = __shfl(sc, lg * 4 + r);
#pragma unroll
    for (int cf = 0; cf < 16; ++cf)
#pragma unroll
      for (int r = 0; r < 4; ++r) accv[cf][r] *= scr[r];

    __syncthreads();  // all waves done reading K tile

    // ---- write P (bf16) into K region rows [wave*16, +16), swizzled ----
    char* pbase = smem + (wave * 16 + lm) * 128;
#pragma unroll
    for (int kf = 0; kf < 4; ++kf) {
      uint2 w;
      w.x = pack2bf(sf[kf][0], sf[kf][1]);
      w.y = pack2bf(sf[kf][2], sf[kf][3]);
      *reinterpret_cast<uint2*>(pbase + (((2 * kf + (lg >> 1)) ^ sw) << 4) + (lg & 1) * 8) = w;
    }

    // ---- PV: accv[cf] += P x V ----
#pragma unroll
    for (int kk = 0; kk < 2; ++kk) {
      bf16x8 pa = *reinterpret_cast<const bf16x8*>(pbase + (((4 * kk + lg) ^ sw) << 4));
#pragma unroll
      for (int cf = 0; cf < 16; ++cf) {
        bf16x8 bvv = *reinterpret_cast<const bf16x8*>(
            smem + 8192 + (cf * 16 + lm) * 128 + (((4 * kk + lg) ^ sw) << 4));
        accv[cf] = __builtin_amdgcn_mfma_f32_16x16x32_bf16(pa, bvv, accv[cf], 0, 0, 0);
      }
    }
    __syncthreads();  // V/P region free for next stage
  }

  // ---- epilogue: out = gamma/lsum * acc + source, via LDS transpose ----
  float* Tl = (float*)smem;  // 64 x 65 f32 = 16640 B (aliases K+V tiles)
  float inv = gamma[0] / lrow;
  float il[4];
#pragma unroll
  for (int r = 0; r < 4; ++r) il[r] = __shfl(inv, lg * 4 + r);

  for (int grp = 0; grp < 4; ++grp) {
#pragma unroll
    for (int cfl = 0; cfl < 4; ++cfl) {
      int cf = grp * 4 + cfl;
#pragma unroll
      for (int r = 0; r < 4; ++r)
        Tl[(wave * 16 + lg * 4 + r) * 65 + cfl * 16 + lm] = accv[cf][r] * il[r];
    }
    __syncthreads();
    const int nl = t & 63;
    const int cl2 = t >> 6;
#pragma unroll
    for (int i = 0; i < 16; ++i) {
      int c = grp * 64 + cl2 + i * 4;
      size_t gi = ((size_t)(b * C_ + c)) * N_ + q0 + nl;
      out[gi] = Tl[nl * 65 + cl2 + i * 4] + source[gi];
    }
    __syncthreads();
  }
}

extern "C" void kernel_launch(void* const* d_in, const int* in_sizes, int n_in,
                              void* d_out, int out_size, void* d_ws, size_t ws_size,
                              hipStream_t stream) {
  const float* src = (const float*)d_in[0];
  const float* gui = (const float*)d_in[1];
  const float* Wq  = (const float*)d_in[2];
  const float* Wk  = (const float*)d_in[3];
  const float* Wv  = (const float*)d_in[4];
  const float* bv  = (const float*)d_in[5];
  const float* gm  = (const float*)d_in[6];
  float* out = (float*)d_out;

  u16* Qb = (u16*)d_ws;                         // 4 MB
  u16* Kb = Qb + (size_t)B_ * N_ * CR_;         // 4 MB
  u16* Vb = Kb + (size_t)B_ * N_ * CR_;         // 16 MB

  proj_kernel<<<dim3(8, B_, 12), dim3(256), 0, stream>>>(src, gui, Wq, Wk, Wv, bv, Qb, Kb, Vb);
  attn_kernel<<<dim3(N_ / 64, B_), dim3(256), 0, stream>>>(Qb, Kb, Vb, src, gm, out);
}